// Round 2
// baseline (1844.960 us; speedup 1.0000x reference)
//
#include <hip/hip_runtime.h>
#include <math.h>

#define D 256
#define K 1024
#define NR 65536
#define BM 64
#define TPB 256
#define ST_SIZE (NR * D)          // 16777216
#define LOSS_OFF ST_SIZE
#define IDX_OFF (ST_SIZE + 1)

// (value,index) ordering: smaller value wins; tie -> smaller index (numpy argmin)
__device__ __forceinline__ bool lessVI(float v, int i, float w, int j) {
    return (v < w) || (v == w && i < j);
}

// square with anti-contraction barrier: keeps fl(x*x) as a separately-rounded
// mul so the following add cannot be fused into fma (hipcc default
// -ffp-contract=fast would otherwise change the numerics vs numpy).
__device__ __forceinline__ float sq_nf(float x) {
    float s = x * x;
    asm volatile("" : "+v"(s));
    return s;
}

// Exact replication of numpy pairwise_sum for sum(a*a) over 256 contiguous
// elements: n=256 > PW_BLOCKSIZE(128) -> two halves of 128; each half uses
// 8 accumulators striding 8, combined ((r0+r1)+(r2+r3))+((r4+r5)+(r6+r7));
// total = left + right.
template <typename F>
__device__ __forceinline__ float np_sumsq256(F ld) {
    float tot[2];
    #pragma unroll
    for (int h = 0; h < 2; ++h) {
        const int base = h * 128;
        float r[8];
        #pragma unroll
        for (int j = 0; j < 8; ++j) r[j] = sq_nf(ld(base + j));
        for (int i = 8; i < 128; i += 8) {
            #pragma unroll
            for (int j = 0; j < 8; ++j) {
                float s = sq_nf(ld(base + i + j));
                r[j] += s;
            }
        }
        tot[h] = ((r[0] + r[1]) + (r[2] + r[3])) + ((r[4] + r[5]) + (r[6] + r[7]));
    }
    return tot[0] + tot[1];
}

// ---------------- per-code ||e||^2 with numpy-pairwise order ---------------
__global__ void se_kernel(const float* __restrict__ emb, float* __restrict__ se) {
    int k = blockIdx.x * blockDim.x + threadIdx.x;
    if (k >= K) return;
    const float* row = emb + (size_t)k * D;
    se[k] = np_sumsq256([&](int i) { return row[i]; });
}

// ---------------- main: f32-faithful distances + argmin + st + loss --------
__global__ __launch_bounds__(TPB, 2)
void vq_main(const float* __restrict__ inp, const float* __restrict__ emb,
             const float* __restrict__ se, float* __restrict__ out,
             double* __restrict__ loss_acc) {
    __shared__ float xs[BM][D + 4];      // 66560 B
    __shared__ float se_s[K];            //  4096 B
    __shared__ float sxs[BM];            //   256 B
    __shared__ float mv[BM][16];         //  4096 B
    __shared__ int   mi[BM][16];         //  4096 B
    __shared__ int   rfinal[BM];         //   256 B
    __shared__ double lred[TPB];         //  2048 B   (total ~81.4 KB -> 2 blocks/CU)

    const int r0  = blockIdx.x * BM;
    const int tid = threadIdx.x;

    // stage X tile (coalesced) + se table
    #pragma unroll
    for (int i = 0; i < (BM * D) / TPB; ++i) {
        int e = i * TPB + tid;
        xs[e >> 8][e & 255] = inp[(size_t)r0 * D + e];
    }
    #pragma unroll
    for (int i = 0; i < K / TPB; ++i) se_s[i * TPB + tid] = se[i * TPB + tid];
    __syncthreads();

    // per-row ||x||^2 with numpy-pairwise order (the one term whose exact
    // rounding decides f32-grid ties at magnitude ~256)
    if (tid < BM) {
        const int row = tid;
        sxs[row] = np_sumsq256([&](int i) { return xs[row][i]; });
    }
    __syncthreads();

    const int tc = tid & 15;                   // code group (16 codes x 4 passes)
    const int tr = tid >> 4;                   // row group: rows tr*4 .. tr*4+3

    float sxr[4];
    #pragma unroll
    for (int rr = 0; rr < 4; ++rr) sxr[rr] = sxs[tr * 4 + rr];

    float bv[4]; int bi[4];
    #pragma unroll
    for (int rr = 0; rr < 4; ++rr) { bv[rr] = INFINITY; bi[rr] = K; }

    for (int pass = 0; pass < 4; ++pass) {
        const int cb = pass * 256 + tc * 16;
        float acc[4][16];
        #pragma unroll
        for (int rr = 0; rr < 4; ++rr)
            #pragma unroll
            for (int cc = 0; cc < 16; ++cc) acc[rr][cc] = 0.f;

        for (int d4 = 0; d4 < 64; ++d4) {
            float4 xv[4];
            #pragma unroll
            for (int rr = 0; rr < 4; ++rr)
                xv[rr] = *(const float4*)&xs[tr * 4 + rr][d4 * 4];
            #pragma unroll
            for (int cc = 0; cc < 16; ++cc) {
                float4 ev = *(const float4*)&emb[(size_t)(cb + cc) * D + d4 * 4];
                #pragma unroll
                for (int rr = 0; rr < 4; ++rr) {
                    acc[rr][cc] = fmaf(xv[rr].x, ev.x, acc[rr][cc]);
                    acc[rr][cc] = fmaf(xv[rr].y, ev.y, acc[rr][cc]);
                    acc[rr][cc] = fmaf(xv[rr].z, ev.z, acc[rr][cc]);
                    acc[rr][cc] = fmaf(xv[rr].w, ev.w, acc[rr][cc]);
                }
            }
        }
        // d = fl( fl(sx + se) - 2*dot )  -- matches numpy (sx+se) - 2.0*mm:
        // t is a lone f32 add; t - 2*acc contracts to fma(-2,acc,t) which is
        // bitwise fl(t - 2*acc), identical to numpy since fl(2*acc)=2*acc.
        #pragma unroll
        for (int cc = 0; cc < 16; ++cc) {
            const int code = cb + cc;
            const float sek = se_s[code];
            #pragma unroll
            for (int rr = 0; rr < 4; ++rr) {
                float t  = sxr[rr] + sek;
                float dv = t - 2.f * acc[rr][cc];
                if (lessVI(dv, code, bv[rr], bi[rr])) { bv[rr] = dv; bi[rr] = code; }
            }
        }
    }

    // per-thread minima -> LDS, then simple serial merge per row (associative
    // VI-min, so order is irrelevant; scan tc=0..15 anyway)
    #pragma unroll
    for (int rr = 0; rr < 4; ++rr) {
        mv[tr * 4 + rr][tc] = bv[rr];
        mi[tr * 4 + rr][tc] = bi[rr];
    }
    __syncthreads();

    if (tid < BM) {
        const int row = tid;
        float v = mv[row][0]; int ix = mi[row][0];
        #pragma unroll
        for (int g = 1; g < 16; ++g) {
            if (lessVI(mv[row][g], mi[row][g], v, ix)) { v = mv[row][g]; ix = mi[row][g]; }
        }
        rfinal[row] = ix;
        out[IDX_OFF + r0 + row] = (float)ix;
    }
    __syncthreads();

    // st = x + (q - x) in f32 (matches reference expression), loss partials
    double lp = 0.0;
    for (int row = 0; row < BM; ++row) {
        const int d = tid;
        float x = xs[row][d];
        float q = emb[(size_t)rfinal[row] * D + d];
        float diff = q - x;
        out[(size_t)(r0 + row) * D + d] = x + diff;
        lp += (double)diff * (double)diff;
    }
    lred[tid] = lp;
    __syncthreads();
    #pragma unroll
    for (int s = 128; s; s >>= 1) {
        if (tid < s) lred[tid] += lred[tid + s];
        __syncthreads();
    }
    if (tid == 0) atomicAdd(loss_acc, lred[0]);
}

// ---------------- finalize loss: (codebook + 0.25*commit) = 1.25*mean ------
__global__ void fin_kernel(const double* __restrict__ loss_acc, float* __restrict__ out) {
    out[LOSS_OFF] = (float)(1.25 * loss_acc[0] / (double)ST_SIZE);
}

extern "C" void kernel_launch(void* const* d_in, const int* in_sizes, int n_in,
                              void* d_out, int out_size, void* d_ws, size_t ws_size,
                              hipStream_t stream) {
    const float* inp = (const float*)d_in[0];
    const float* emb = (const float*)d_in[1];
    float* out = (float*)d_out;
    float*  se       = (float*)d_ws;                      // 4 KB
    double* loss_acc = (double*)((char*)d_ws + 8192);     // 8 B, aligned

    hipMemsetAsync(loss_acc, 0, sizeof(double), stream);
    se_kernel<<<K / TPB, TPB, 0, stream>>>(emb, se);
    vq_main<<<NR / BM, TPB, 0, stream>>>(inp, emb, se, out, loss_acc);
    fin_kernel<<<1, 1, 0, stream>>>(loss_acc, out);
}

// Round 3
// 256.134 us; speedup vs baseline: 7.2031x; 7.2031x over previous
//
#include <hip/hip_runtime.h>
#include <math.h>

#define D 256
#define K 1024
#define NR 65536
#define ST_SIZE (NR * D)          // 16777216
#define LOSS_OFF ST_SIZE
#define IDX_OFF (ST_SIZE + 1)
#define BMAIN 256
#define NCG 32
#define MARGIN 1e-3f
#define CAND_CAP 2048

typedef short bf16x8 __attribute__((ext_vector_type(8)));
typedef float f32x16 __attribute__((ext_vector_type(16)));

// f32 -> bf16 RNE (bit-level)
__device__ __forceinline__ unsigned f2bf(float f) {
    unsigned u = __float_as_uint(f);
    return (u + 0x7FFFu + ((u >> 16) & 1u)) >> 16;
}
__device__ __forceinline__ uint4 packB(float4 a, float4 b) {
    uint4 w;
    w.x = f2bf(-2.f * a.x) | (f2bf(-2.f * a.y) << 16);
    w.y = f2bf(-2.f * a.z) | (f2bf(-2.f * a.w) << 16);
    w.z = f2bf(-2.f * b.x) | (f2bf(-2.f * b.y) << 16);
    w.w = f2bf(-2.f * b.z) | (f2bf(-2.f * b.w) << 16);
    return w;
}

// anti-contraction square (keeps numpy-identical rounding)
__device__ __forceinline__ float sq_nf(float x) {
    float s = x * x;
    asm volatile("" : "+v"(s));
    return s;
}
// numpy pairwise sum of squares over 256 elements (validated bit-exact in r2)
template <typename F>
__device__ __forceinline__ float np_sumsq256(F ld) {
    float tot[2];
    #pragma unroll
    for (int h = 0; h < 2; ++h) {
        const int base = h * 128;
        float r[8];
        #pragma unroll
        for (int j = 0; j < 8; ++j) r[j] = sq_nf(ld(base + j));
        for (int i = 8; i < 128; i += 8) {
            #pragma unroll
            for (int j = 0; j < 8; ++j) r[j] += sq_nf(ld(base + i + j));
        }
        tot[h] = ((r[0] + r[1]) + (r[2] + r[3])) + ((r[4] + r[5]) + (r[6] + r[7]));
    }
    return tot[0] + tot[1];
}

__global__ void se_kernel(const float* __restrict__ emb, float* __restrict__ se) {
    int k = blockIdx.x * blockDim.x + threadIdx.x;
    if (k >= K) return;
    const float* row = emb + (size_t)k * D;
    se[k] = np_sumsq256([&](int i) { return row[i]; });
}

__global__ void sx_kernel(const float* __restrict__ inp, float* __restrict__ sx) {
    __shared__ float xs[64][257];
    const int r0 = blockIdx.x * 64;
    const int tid = threadIdx.x;
    #pragma unroll
    for (int i = 0; i < 64; ++i) {
        int e = i * 256 + tid;
        xs[e >> 8][e & 255] = inp[(size_t)r0 * D + e];
    }
    __syncthreads();
    if (tid < 64) {
        const int row = tid;
        sx[r0 + row] = np_sumsq256([&](int i) { return xs[row][i]; });
    }
}

// main: bf16-MFMA prune (2 sweeps) + exact f32 rescore + fused st/loss
__global__ __launch_bounds__(512, 1)
void vq_mfma(const float* __restrict__ inp, const float* __restrict__ emb,
             const float* __restrict__ se, const float* __restrict__ sx,
             float* __restrict__ out, double* __restrict__ loss_acc) {
    __shared__ __align__(16) unsigned short Bt[2][16 * 64 * 8];  // 2 x 16KB
    __shared__ float se_s[K];
    __shared__ float sx_s[BMAIN];
    __shared__ unsigned int cand[CAND_CAP];
    __shared__ float candd[CAND_CAP];
    __shared__ unsigned int bestd[BMAIN];
    __shared__ unsigned int bestc[BMAIN];
    __shared__ double lred[512];
    __shared__ int ncand;

    const int t   = threadIdx.x;
    const int ws  = t >> 6;     // wave 0..7
    const int l   = t & 63;     // lane
    const int col = l & 31;     // MFMA col / A row-in-tile
    const int hi  = l >> 5;
    const int r0  = blockIdx.x * BMAIN;

    #pragma unroll
    for (int i = 0; i < K / 512; ++i) se_s[i * 512 + t] = se[i * 512 + t];
    if (t < BMAIN) { sx_s[t] = sx[r0 + t]; bestd[t] = 0xFFFFFFFFu; bestc[t] = 0xFFFFFFFFu; }
    if (t == 0) ncand = 0;

    // ---- A fragments in registers: rows r0+ws*32+col, k = ks*16 + hi*8 + j ----
    bf16x8 afr[16];
    {
        const float* xrow = inp + (size_t)(r0 + ws * 32 + col) * D;
        #pragma unroll
        for (int ks = 0; ks < 16; ++ks) {
            const float4* p = (const float4*)(xrow + ks * 16 + hi * 8);
            float4 a = p[0], b = p[1];
            bf16x8 v;
            v[0] = (short)f2bf(a.x); v[1] = (short)f2bf(a.y);
            v[2] = (short)f2bf(a.z); v[3] = (short)f2bf(a.w);
            v[4] = (short)f2bf(b.x); v[5] = (short)f2bf(b.y);
            v[6] = (short)f2bf(b.z); v[7] = (short)f2bf(b.w);
            afr[ks] = v;
        }
    }

    float rmin[16];
    #pragma unroll
    for (int i = 0; i < 16; ++i) rmin[i] = INFINITY;

    // B staging decode for this thread's two 16B chunks (u = c*512 + t)
    const int u0 = t, u1 = 512 + t;
    const int ks0 = u0 >> 6, l60 = u0 & 63;
    const int ks1 = u1 >> 6, l61 = u1 & 63;
    const float* b0base = emb + (size_t)(l60 & 31) * D + ks0 * 16 + (l60 >> 5) * 8;
    const float* b1base = emb + (size_t)(l61 & 31) * D + ks1 * 16 + (l61 >> 5) * 8;

    auto run_sweep = [&](int sweep) {
        int cur = 0;
        {   // prologue: stage cg 0 into Bt[0]
            const float4* s0 = (const float4*)b0base;
            const float4* s1 = (const float4*)b1base;
            float4 a0 = s0[0], c0 = s0[1], a1 = s1[0], c1 = s1[1];
            uint4* bt = (uint4*)&Bt[0][0];
            bt[u0] = packB(a0, c0);
            bt[u1] = packB(a1, c1);
        }
        for (int cg = 0; cg < NCG; ++cg) {
            __syncthreads();                       // Bt[cur] ready
            float4 a0, c0, a1, c1;
            const bool pf = (cg + 1 < NCG);
            if (pf) {                              // prefetch next tile (hidden under MFMA)
                const size_t off = (size_t)(cg + 1) * 32 * D;
                const float4* s0 = (const float4*)(b0base + off);
                const float4* s1 = (const float4*)(b1base + off);
                a0 = s0[0]; c0 = s0[1]; a1 = s1[0]; c1 = s1[1];
            }
            // ---- compute: score = se - 2*x.e via MFMA, C-init = se[col] ----
            const float sev = se_s[cg * 32 + col];
            f32x16 acc;
            #pragma unroll
            for (int i = 0; i < 16; ++i) acc[i] = sev;
            const bf16x8* bp = (const bf16x8*)&Bt[cur][0];
            #pragma unroll
            for (int ks = 0; ks < 16; ++ks) {
                bf16x8 bf = bp[ks * 64 + l];
                acc = __builtin_amdgcn_mfma_f32_32x32x16_bf16(afr[ks], bf, acc, 0, 0, 0);
            }
            if (!sweep) {
                #pragma unroll
                for (int i = 0; i < 16; ++i) rmin[i] = fminf(rmin[i], acc[i]);
            } else {
                #pragma unroll
                for (int i = 0; i < 16; ++i) {
                    if (acc[i] <= rmin[i] + MARGIN) {
                        int row_local = ws * 32 + (i & 3) + 8 * (i >> 2) + 4 * hi;
                        int code = cg * 32 + col;
                        int p = atomicAdd(&ncand, 1);
                        if (p < CAND_CAP) cand[p] = ((unsigned)row_local << 10) | (unsigned)code;
                    }
                }
            }
            if (pf) {
                uint4* bt = (uint4*)&Bt[cur ^ 1][0];
                bt[u0] = packB(a0, c0);
                bt[u1] = packB(a1, c1);
            }
            cur ^= 1;
        }
    };

    run_sweep(0);
    // per-row min across the 32 lanes sharing each row (xor stays in 32-half)
    #pragma unroll
    for (int i = 0; i < 16; ++i) {
        #pragma unroll
        for (int m = 1; m < 32; m <<= 1)
            rmin[i] = fminf(rmin[i], __shfl_xor(rmin[i], m));
    }
    __syncthreads();
    run_sweep(1);
    __syncthreads();                               // candidate list complete

    // ---- exact f32 rescore (wave-cooperative), numpy-faithful d ----
    int n = ncand; if (n > CAND_CAP) n = CAND_CAP;
    for (int ci = ws; ci < n; ci += 8) {
        const unsigned uc = cand[ci];
        const int row_local = uc >> 10, code = uc & 1023;
        const float4 xv = ((const float4*)(inp + (size_t)(r0 + row_local) * D))[l];
        const float4 ev = ((const float4*)(emb + (size_t)code * D))[l];
        float p = xv.x * ev.x;
        p = fmaf(xv.y, ev.y, p);
        p = fmaf(xv.z, ev.z, p);
        p = fmaf(xv.w, ev.w, p);
        #pragma unroll
        for (int m = 1; m < 64; m <<= 1) p += __shfl_xor(p, m);
        const float tv = sx_s[row_local] + se_s[code];
        const float d  = fmaf(-2.f, p, tv);        // = fl(t - 2*dot), matches numpy
        if (l == 0) {
            candd[ci] = d;
            atomicMin(&bestd[row_local], __float_as_uint(d));
        }
    }
    __syncthreads();
    for (int ci = t; ci < n; ci += 512) {          // tie-break: lowest code at min d
        const unsigned uc = cand[ci];
        const int row_local = uc >> 10, code = uc & 1023;
        if (__float_as_uint(candd[ci]) == bestd[row_local])
            atomicMin(&bestc[row_local], (unsigned)code);
    }
    __syncthreads();
    if (t < BMAIN) out[IDX_OFF + r0 + t] = (float)bestc[t];

    // ---- fused epilogue: st + loss ----
    double lp = 0.0;
    const size_t base = (size_t)r0 * D;
    for (int i = 0; i < (BMAIN * D) / 512; ++i) {
        const int e = i * 512 + t;
        const int row = e >> 8, dd = e & 255;
        const float x = inp[base + e];
        const float q = emb[(size_t)bestc[row] * D + dd];
        const float diff = q - x;
        out[base + e] = x + diff;
        lp += (double)diff * (double)diff;
    }
    lred[t] = lp;
    __syncthreads();
    #pragma unroll
    for (int s = 256; s; s >>= 1) {
        if (t < s) lred[t] += lred[t + s];
        __syncthreads();
    }
    if (t == 0) atomicAdd(loss_acc, lred[0]);
}

__global__ void fin_kernel(const double* __restrict__ loss_acc, float* __restrict__ out) {
    out[LOSS_OFF] = (float)(1.25 * loss_acc[0] / (double)ST_SIZE);
}

extern "C" void kernel_launch(void* const* d_in, const int* in_sizes, int n_in,
                              void* d_out, int out_size, void* d_ws, size_t ws_size,
                              hipStream_t stream) {
    const float* inp = (const float*)d_in[0];
    const float* emb = (const float*)d_in[1];
    float* out = (float*)d_out;
    float*  sx_ws    = (float*)d_ws;                          // 256 KB
    float*  se_ws    = (float*)((char*)d_ws + 262144);        //   4 KB
    double* loss_acc = (double*)((char*)d_ws + 266240);       //   8 B

    hipMemsetAsync(loss_acc, 0, sizeof(double), stream);
    se_kernel<<<K / 256, 256, 0, stream>>>(emb, se_ws);
    sx_kernel<<<NR / 64, 256, 0, stream>>>(inp, sx_ws);
    vq_mfma<<<NR / BMAIN, 512, 0, stream>>>(inp, emb, se_ws, sx_ws, out, loss_acc);
    fin_kernel<<<1, 1, 0, stream>>>(loss_acc, out);
}

// Round 5
// 189.640 us; speedup vs baseline: 9.7287x; 1.3506x over previous
//
#include <hip/hip_runtime.h>
#include <math.h>

#define D 256
#define K 1024
#define NR 65536
#define ST_SIZE (NR * D)          // 16777216
#define LOSS_OFF ST_SIZE
#define IDX_OFF (ST_SIZE + 1)
#define BM 256
#define TPB 512
#define NCG 32
#define MARGIN 2e-3f
#define CAND_CAP 4096

typedef short bf16x8 __attribute__((ext_vector_type(8)));
typedef float f32x16 __attribute__((ext_vector_type(16)));

// f32 -> bf16 RNE (bit-level)
__device__ __forceinline__ unsigned f2bf(float f) {
    unsigned u = __float_as_uint(f);
    return (u + 0x7FFFu + ((u >> 16) & 1u)) >> 16;
}
__device__ __forceinline__ uint4 packB(float4 a, float4 b) {
    uint4 w;
    w.x = f2bf(-2.f * a.x) | (f2bf(-2.f * a.y) << 16);
    w.y = f2bf(-2.f * a.z) | (f2bf(-2.f * a.w) << 16);
    w.z = f2bf(-2.f * b.x) | (f2bf(-2.f * b.y) << 16);
    w.w = f2bf(-2.f * b.z) | (f2bf(-2.f * b.w) << 16);
    return w;
}

// anti-contraction square (numpy-identical rounding: mul rounded alone)
__device__ __forceinline__ float sq_nf(float x) {
    float s = x * x;
    asm volatile("" : "+v"(s));
    return s;
}
// numpy pairwise sum of squares over 256 elements (bit-exact, validated r2/r3)
template <typename F>
__device__ __forceinline__ float np_sumsq256(F ld) {
    float tot[2];
    #pragma unroll
    for (int h = 0; h < 2; ++h) {
        const int base = h * 128;
        float r[8];
        #pragma unroll
        for (int j = 0; j < 8; ++j) r[j] = sq_nf(ld(base + j));
        for (int i = 8; i < 128; i += 8) {
            #pragma unroll
            for (int j = 0; j < 8; ++j) r[j] += sq_nf(ld(base + i + j));
        }
        tot[h] = ((r[0] + r[1]) + (r[2] + r[3])) + ((r[4] + r[5]) + (r[6] + r[7]));
    }
    return tot[0] + tot[1];
}

// prep: blocks 0..127 pack bf16(-2e) in MFMA fragment order; blocks 128..131 se
__global__ void prep_kernel(const float* __restrict__ emb,
                            unsigned short* __restrict__ pb,
                            float* __restrict__ se) {
    if (blockIdx.x < 128) {
        const int c  = blockIdx.x * 256 + threadIdx.x;    // chunk id, 32768 total
        const int cg = c >> 10, r = c & 1023;
        const int ks = r >> 6,  l = r & 63;
        const float4* s4 = (const float4*)(emb + (size_t)(cg * 32 + (l & 31)) * D
                                               + ks * 16 + (l >> 5) * 8);
        ((uint4*)pb)[c] = packB(s4[0], s4[1]);
    } else {
        const int k = (blockIdx.x - 128) * 256 + threadIdx.x;   // < 1024
        const float* row = emb + (size_t)k * D;
        se[k] = np_sumsq256([&](int i) { return row[i]; });
    }
}

// main: two-sweep MFMA prune (r3-proven skeleton) + exact f32 rescore + st/loss
__global__ __launch_bounds__(TPB, 1)
void vq_mfma(const float* __restrict__ inp, const float* __restrict__ emb,
             const unsigned short* __restrict__ pb, const float* __restrict__ se,
             float* __restrict__ out, double* __restrict__ loss_acc) {
    __shared__ __align__(16) unsigned short Bt[2][8192];   // 2 x 16 KB
    __shared__ float se_s[K];
    __shared__ float sx_s[BM];
    __shared__ unsigned cand[CAND_CAP];
    __shared__ float candd[CAND_CAP];
    __shared__ unsigned bestd[BM];
    __shared__ unsigned bestc[BM];
    __shared__ double lred[TPB];
    __shared__ int ncand;

    const int t   = threadIdx.x;
    const int ws  = t >> 6;      // wave 0..7
    const int l   = t & 63;
    const int col = l & 31;
    const int hi  = l >> 5;
    const int r0  = blockIdx.x * BM;

    #pragma unroll
    for (int i = 0; i < K / TPB; ++i) se_s[i * TPB + t] = se[i * TPB + t];
    if (t < BM) { bestd[t] = 0xFFFFFFFFu; bestc[t] = 0xFFFFFFFFu; }
    if (t == 0) ncand = 0;

    // ---- A fragments: rows r0 + ws*32 + col, k = ks*16 + hi*8 + j ----
    bf16x8 afr[16];
    {
        const float* xrow = inp + (size_t)(r0 + ws * 32 + col) * D;
        #pragma unroll
        for (int ks = 0; ks < 16; ++ks) {
            const float4* p4 = (const float4*)(xrow + ks * 16 + hi * 8);
            float4 a = p4[0], b = p4[1];
            bf16x8 v;
            v[0] = (short)f2bf(a.x); v[1] = (short)f2bf(a.y);
            v[2] = (short)f2bf(a.z); v[3] = (short)f2bf(a.w);
            v[4] = (short)f2bf(b.x); v[5] = (short)f2bf(b.y);
            v[6] = (short)f2bf(b.z); v[7] = (short)f2bf(b.w);
            afr[ks] = v;
        }
    }

    // ---- fused sx: numpy-pairwise-exact, 16 lanes per row (pure shfl) ----
    {
        const int slot = t & 15, grp = t >> 4;   // 32 groups of 16 lanes
        const int j = slot & 7, h = slot >> 3;
        for (int p = 0; p < 8; ++p) {
            const int row = p * 32 + grp;
            const float* base = inp + (size_t)(r0 + row) * D + h * 128 + j;
            float s = sq_nf(base[0]);
            #pragma unroll
            for (int i = 1; i < 16; ++i) s += sq_nf(base[i * 8]);
            #pragma unroll
            for (int m = 1; m <= 8; m <<= 1) s += __shfl_xor(s, m);  // local-left
            if (slot == 0) sx_s[row] = s;
        }
    }

    float rmin[16];
    #pragma unroll
    for (int i = 0; i < 16; ++i) rmin[i] = INFINITY;

    const uint4* src = (const uint4*)pb;
    const int u0 = t, u1 = TPB + t;              // this thread's two tile chunks

    auto run_sweep = [&](int sweep) {
        int cur = 0;
        {   // prologue: stage cg 0 (coalesced copy of pre-packed bf16)
            uint4* bt = (uint4*)&Bt[0][0];
            bt[u0] = src[u0];
            bt[u1] = src[u1];
        }
        for (int cg = 0; cg < NCG; ++cg) {
            __syncthreads();                       // Bt[cur] published
            uint4 pf0, pf1;
            const bool pf = (cg + 1 < NCG);
            if (pf) {                              // prefetch next tile to regs
                pf0 = src[(size_t)(cg + 1) * 1024 + u0];
                pf1 = src[(size_t)(cg + 1) * 1024 + u1];
            }
            // score = se - 2*x.e via MFMA, C-init = se[col]
            const float sev = se_s[cg * 32 + col];
            f32x16 acc;
            #pragma unroll
            for (int i = 0; i < 16; ++i) acc[i] = sev;
            const bf16x8* bp = (const bf16x8*)&Bt[cur][0];
            #pragma unroll
            for (int ks = 0; ks < 16; ++ks)
                acc = __builtin_amdgcn_mfma_f32_32x32x16_bf16(afr[ks], bp[ks * 64 + l], acc, 0, 0, 0);

            if (!sweep) {
                #pragma unroll
                for (int i = 0; i < 16; ++i) rmin[i] = fminf(rmin[i], acc[i]);
            } else {
                // flag vs EXACT final per-row min + margin (superset of f32 argmin)
                #pragma unroll
                for (int i = 0; i < 16; ++i) {
                    if (acc[i] <= rmin[i] + MARGIN) {
                        const int row_local = ws * 32 + (i & 3) + 8 * (i >> 2) + 4 * hi;
                        const int p = atomicAdd(&ncand, 1);
                        if (p < CAND_CAP)
                            cand[p] = ((unsigned)row_local << 10) | (unsigned)(cg * 32 + col);
                    }
                }
            }
            if (pf) {                              // write next tile (r3-proven pattern)
                uint4* bt = (uint4*)&Bt[cur ^ 1][0];
                bt[u0] = pf0;
                bt[u1] = pf1;
            }
            cur ^= 1;
        }
    };

    run_sweep(0);
    // per-row exact min across the 32 lanes sharing each row
    #pragma unroll
    for (int i = 0; i < 16; ++i) {
        #pragma unroll
        for (int m = 1; m < 32; m <<= 1)
            rmin[i] = fminf(rmin[i], __shfl_xor(rmin[i], m));
    }
    __syncthreads();
    run_sweep(1);
    __syncthreads();                               // candidate list complete

    // ---- exact f32 rescore (wave per candidate), numpy-faithful d ----
    int n = ncand; if (n > CAND_CAP) n = CAND_CAP;
    for (int ci = ws; ci < n; ci += 8) {
        const unsigned uc = cand[ci];
        const int row_local = uc >> 10, code = uc & 1023;
        const float4 xv = ((const float4*)(inp + (size_t)(r0 + row_local) * D))[l];
        const float4 ev = ((const float4*)(emb + (size_t)code * D))[l];
        float p = xv.x * ev.x;
        p = fmaf(xv.y, ev.y, p);
        p = fmaf(xv.z, ev.z, p);
        p = fmaf(xv.w, ev.w, p);
        #pragma unroll
        for (int m = 1; m < 64; m <<= 1) p += __shfl_xor(p, m);
        const float tv = sx_s[row_local] + se_s[code];
        const float d  = fmaf(-2.f, p, tv);        // = fl(t - 2*dot), matches numpy
        if (l == 0) {
            candd[ci] = d;
            atomicMin(&bestd[row_local], __float_as_uint(d));   // d > 0: uint-monotone
        }
    }
    __syncthreads();
    for (int ci = t; ci < n; ci += TPB) {          // tie-break: lowest code at min d
        const unsigned uc = cand[ci];
        const int row_local = uc >> 10, code = uc & 1023;
        if (__float_as_uint(candd[ci]) == bestd[row_local])
            atomicMin(&bestc[row_local], (unsigned)code);
    }
    __syncthreads();
    if (t < BM) out[IDX_OFF + r0 + t] = (float)bestc[t];

    // ---- fused epilogue: st + loss ----
    double lp = 0.0;
    const size_t base = (size_t)r0 * D;
    for (int i = 0; i < (BM * D) / TPB; ++i) {
        const int e = i * TPB + t;
        const int row = e >> 8, dd = e & 255;
        const float x = inp[base + e];
        const float q = emb[(size_t)bestc[row] * D + dd];
        const float diff = q - x;
        out[base + e] = x + diff;
        lp += (double)diff * (double)diff;
    }
    lred[t] = lp;
    __syncthreads();
    #pragma unroll
    for (int s = 256; s; s >>= 1) {
        if (t < s) lred[t] += lred[t + s];
        __syncthreads();
    }
    if (t == 0) atomicAdd(loss_acc, lred[0]);
}

__global__ void fin_kernel(const double* __restrict__ loss_acc, float* __restrict__ out) {
    out[LOSS_OFF] = (float)(1.25 * loss_acc[0] / (double)ST_SIZE);
}

extern "C" void kernel_launch(void* const* d_in, const int* in_sizes, int n_in,
                              void* d_out, int out_size, void* d_ws, size_t ws_size,
                              hipStream_t stream) {
    const float* inp = (const float*)d_in[0];
    const float* emb = (const float*)d_in[1];
    float* out = (float*)d_out;
    unsigned short* pb = (unsigned short*)d_ws;               // 512 KB (frag-ordered bf16)
    float*  se_ws      = (float*)((char*)d_ws + 524288);      //   4 KB
    double* loss_acc   = (double*)((char*)d_ws + 528384);     //   8 B

    hipMemsetAsync(loss_acc, 0, sizeof(double), stream);
    prep_kernel<<<132, 256, 0, stream>>>(emb, pb, se_ws);
    vq_mfma<<<NR / BM, TPB, 0, stream>>>(inp, emb, pb, se_ws, out, loss_acc);
    fin_kernel<<<1, 1, 0, stream>>>(loss_acc, out);
}